// Round 6
// baseline (118.060 us; speedup 1.0000x reference)
//
#include <hip/hip_runtime.h>
#include <hip/hip_bf16.h>
#include <math.h>

// BoxE scorer:
//   y: (2048, 256) f32 -> boxes: mn = y[:, :128], delta = softplus(y[:, 128:])
//   x: (1024, 128) f32 -> points
//   out[m][n] = -|| per_dim(x[m], box[n]) ||_2, shape (1024, 2048) f32
//
// per_dim (k-th):
//   center = mn + delta/2 ; dp1 = delta+1 ; l1 = |x - center|
//   inside (|x-center| <= delta/2): l1 / (dp1 + 1e-10)
//   outside: l1*dp1 - c2,  c2 = delta/2*(delta - 1/(delta+1e-10))
//
// R5: prep was ~53us (uncoalesced 1KiB-stride y reads). Rewritten as
// transpose-through-LDS: coalesced k-fastest reads of y, padded LDS [128][9]
// per component (stride 9 coprime 32 -> conflict-free), coalesced n-fastest
// writes of p4[k][n]. xT dropped: main stages x directly (k-fastest coalesced
// read, padded xtile[128][33] write). Main: unroll 8 for deeper load batching.

#define BM 32
#define BN 64
#define TM 8

// ---- prep: y (2048,256) -> p4[k][n] = {center, hd, inv, c2}, [128][2048] ----
// block = 256 threads, n-tile = 8 boxes, all 128 k. grid = 256 blocks.
__global__ __launch_bounds__(256) void boxe_prep(const float* __restrict__ y,
                                                 float4* __restrict__ p4)
{
    __shared__ float t0[128][9], t1[128][9], t2[128][9], t3[128][9];
    const int tid = threadIdx.x;
    const int n0  = blockIdx.x * 8;

    // phase 1: k-fastest mapping -> coalesced y reads (256B/wave)
#pragma unroll
    for (int i = 0; i < 4; ++i) {
        int j  = i * 256 + tid;        // 0..1023 = 8 n x 128 k
        int k  = j & 127;
        int nl = j >> 7;
        int n  = n0 + nl;
        float mn = y[n * 256 + k];
        float dv = y[n * 256 + 128 + k];
        // stable softplus: max(v,0) + log1p(exp(-|v|))  (matches jax.nn.softplus)
        float delta = fmaxf(dv, 0.0f) + log1pf(expf(-fabsf(dv)));
        float hd  = 0.5f * delta;
        t0[k][nl] = mn + hd;                              // center
        t1[k][nl] = hd;                                   // half-width
        t2[k][nl] = 1.0f / (delta + 1.0f + 1e-10f);       // 1/(dp1+eps)
        t3[k][nl] = hd * (delta - 1.0f / (delta + 1e-10f)); // c2
    }
    __syncthreads();

    // phase 2: n-fastest mapping -> coalesced p4 writes (8x128B segs/wave)
#pragma unroll
    for (int i = 0; i < 4; ++i) {
        int j  = i * 256 + tid;
        int nl = j & 7;
        int k  = j >> 3;
        p4[k * 2048 + n0 + nl] =
            make_float4(t0[k][nl], t1[k][nl], t2[k][nl], t3[k][nl]);
    }
}

// ---- main: out[m][n] = -sqrt( sum_k per_dim^2 ) ----
__global__ __launch_bounds__(256) void boxe_main(
    const float4* __restrict__ p4, const float* __restrict__ x,
    float* __restrict__ out)
{
    __shared__ float xtile[128][BM + 1];   // pad: write stride 33 (coprime 32)

    const int tid  = threadIdx.x;
    const int lane = tid & 63;
    const int wave = tid >> 6;
    const int m0   = blockIdx.y * BM;
    const int n0   = blockIdx.x * BN;

    // Stage x tile directly from x: k-fastest -> coalesced 256B/wave reads.
#pragma unroll
    for (int i = 0; i < (128 * BM) / 256; ++i) {
        int idx = i * 256 + tid;       // 32 m x 128 k
        int m = idx >> 7;
        int k = idx & 127;
        xtile[k][m] = x[(m0 + m) * 128 + k];
    }
    __syncthreads();

    float acc[TM];
#pragma unroll
    for (int r = 0; r < TM; ++r) acc[r] = 0.0f;

    const int n  = n0 + lane;     // one box per lane, coalesced float4 loads
    const int mw = wave * TM;     // this wave's m-offset within tile

#pragma unroll 8
    for (int k = 0; k < 128; ++k) {
        float4 p = p4[k * 2048 + n];              // {center, hd, inv, c2}
        float dp1 = fmaf(2.0f, p.y, 1.0f);        // delta+1, exact
#pragma unroll
        for (int r = 0; r < TM; ++r) {
            float xv = xtile[k][mw + r];          // uniform addr -> LDS broadcast
            float l = fabsf(xv - p.x);
            float v = (l <= p.y) ? (l * p.z) : fmaf(l, dp1, -p.w);
            acc[r] = fmaf(v, v, acc[r]);
        }
    }

#pragma unroll
    for (int r = 0; r < TM; ++r) {
        int m = m0 + mw + r;
        out[m * 2048 + n] = -sqrtf(acc[r]);
    }
}

extern "C" void kernel_launch(void* const* d_in, const int* in_sizes, int n_in,
                              void* d_out, int out_size, void* d_ws, size_t ws_size,
                              hipStream_t stream) {
    const float* y = (const float*)d_in[0];   // 2048*256
    const float* x = (const float*)d_in[1];   // 1024*128
    float* out = (float*)d_out;               // 1024*2048

    float4* p4 = (float4*)d_ws;               // 4 MiB: [128][2048] float4

    hipLaunchKernelGGL(boxe_prep, dim3(2048 / 8), dim3(256), 0, stream, y, p4);

    dim3 grid(2048 / BN, 1024 / BM);          // (32, 32) = 1024 blocks
    hipLaunchKernelGGL(boxe_main, grid, dim3(256), 0, stream, p4, x, out);
}

// Round 9
// 111.905 us; speedup vs baseline: 1.0550x; 1.0550x over previous
//
#include <hip/hip_runtime.h>
#include <hip/hip_bf16.h>
#include <math.h>

// BoxE scorer:
//   y: (2048, 256) f32 -> boxes: mn = y[:, :128], delta = softplus(y[:, 128:])
//   x: (1024, 128) f32 -> points
//   out[m][n] = -|| per_dim(x[m], box[n]) ||_2, shape (1024, 2048) f32
//
// per_dim (k-th):
//   center = mn + delta/2 ; dp1 = delta+1 ; l1 = |x - center|
//   inside (|x-center| <= delta/2): l1 / (dp1 + 1e-10)
//   outside: l1*dp1 - c2,  c2 = delta/2*(delta - 1/(delta+1e-10))
//
// R7: totals show a fixed ~51us harness overhead (total-main constant across
// R2/R4/R6); only main is controllable. Main was occupancy-capped (1024 blocks
// = 16 waves/CU = 50% max, measured 35%). BM 32->16, TM 8->4 -> 2048 blocks =
// 8 blocks/CU (100% cap), __launch_bounds__(256,8) to keep VGPR<=64. xv reads
// collapsed 4x ds_read_b32 -> 1x ds_read_b128 (xtile stride 20 floats = 80B,
// rows 16B-aligned; staging write 8-way conflict is 32 wave-writes/block,
// negligible).

#define BM 16
#define BN 64
#define TM 4
#define XPAD 20   // floats per xtile row: 16 data + 4 pad (80B, 16B-aligned)

// ---- prep: y (2048,256) -> p4[k][n] = {center, hd, inv, c2}, [128][2048] ----
__global__ __launch_bounds__(256) void boxe_prep(const float* __restrict__ y,
                                                 float4* __restrict__ p4)
{
    __shared__ float t0[128][9], t1[128][9], t2[128][9], t3[128][9];
    const int tid = threadIdx.x;
    const int n0  = blockIdx.x * 8;

    // phase 1: k-fastest mapping -> coalesced y reads (256B/wave)
#pragma unroll
    for (int i = 0; i < 4; ++i) {
        int j  = i * 256 + tid;        // 0..1023 = 8 n x 128 k
        int k  = j & 127;
        int nl = j >> 7;
        int n  = n0 + nl;
        float mn = y[n * 256 + k];
        float dv = y[n * 256 + 128 + k];
        // stable softplus: max(v,0) + log1p(exp(-|v|))  (matches jax.nn.softplus)
        float delta = fmaxf(dv, 0.0f) + log1pf(expf(-fabsf(dv)));
        float hd  = 0.5f * delta;
        t0[k][nl] = mn + hd;                                // center
        t1[k][nl] = hd;                                     // half-width
        t2[k][nl] = 1.0f / (delta + 1.0f + 1e-10f);         // 1/(dp1+eps)
        t3[k][nl] = hd * (delta - 1.0f / (delta + 1e-10f)); // c2
    }
    __syncthreads();

    // phase 2: n-fastest mapping -> coalesced p4 writes
#pragma unroll
    for (int i = 0; i < 4; ++i) {
        int j  = i * 256 + tid;
        int nl = j & 7;
        int k  = j >> 3;
        p4[k * 2048 + n0 + nl] =
            make_float4(t0[k][nl], t1[k][nl], t2[k][nl], t3[k][nl]);
    }
}

// ---- main: out[m][n] = -sqrt( sum_k per_dim^2 ) ----
__global__ __launch_bounds__(256, 8) void boxe_main(
    const float4* __restrict__ p4, const float* __restrict__ x,
    float* __restrict__ out)
{
    __shared__ float xtile[128][XPAD];   // 10.24 KiB

    const int tid  = threadIdx.x;
    const int lane = tid & 63;
    const int wave = tid >> 6;
    const int m0   = blockIdx.y * BM;
    const int n0   = blockIdx.x * BN;

    // Stage x tile: 16 m x 128 k, k-fastest -> coalesced 256B/wave reads.
#pragma unroll
    for (int i = 0; i < (128 * BM) / 256; ++i) {
        int idx = i * 256 + tid;       // 16 m x 128 k
        int m = idx >> 7;
        int k = idx & 127;
        xtile[k][m] = x[(m0 + m) * 128 + k];
    }
    __syncthreads();

    float acc[TM];
#pragma unroll
    for (int r = 0; r < TM; ++r) acc[r] = 0.0f;

    const int n  = n0 + lane;     // one box per lane, coalesced float4 loads
    const int mw = wave * TM;     // this wave's m-offset (0,4,8,12), 16B-aligned

#pragma unroll 8
    for (int k = 0; k < 128; ++k) {
        float4 p  = p4[k * 2048 + n];                       // {center,hd,inv,c2}
        float4 xv = *(const float4*)&xtile[k][mw];          // 1x ds_read_b128
        float dp1 = fmaf(2.0f, p.y, 1.0f);                  // delta+1, exact
#pragma unroll
        for (int r = 0; r < TM; ++r) {
            float xr = (r == 0) ? xv.x : (r == 1) ? xv.y : (r == 2) ? xv.z : xv.w;
            float l = fabsf(xr - p.x);
            float v = (l <= p.y) ? (l * p.z) : fmaf(l, dp1, -p.w);
            acc[r] = fmaf(v, v, acc[r]);
        }
    }

#pragma unroll
    for (int r = 0; r < TM; ++r) {
        int m = m0 + mw + r;
        out[m * 2048 + n] = -sqrtf(acc[r]);
    }
}

extern "C" void kernel_launch(void* const* d_in, const int* in_sizes, int n_in,
                              void* d_out, int out_size, void* d_ws, size_t ws_size,
                              hipStream_t stream) {
    const float* y = (const float*)d_in[0];   // 2048*256
    const float* x = (const float*)d_in[1];   // 1024*128
    float* out = (float*)d_out;               // 1024*2048

    float4* p4 = (float4*)d_ws;               // 4 MiB: [128][2048] float4

    hipLaunchKernelGGL(boxe_prep, dim3(2048 / 8), dim3(256), 0, stream, y, p4);

    dim3 grid(2048 / BN, 1024 / BM);          // (32, 64) = 2048 blocks
    hipLaunchKernelGGL(boxe_main, grid, dim3(256), 0, stream, p4, x, out);
}